// Round 3
// baseline (784.397 us; speedup 1.0000x reference)
//
#include <hip/hip_runtime.h>

// FastSurf fused kernel: trilinear grid gather + density MLP + view-embed + rgb MLP.
// f16 MFMA (16x16x32), activations staged in LDS.
//
// v4 = v3 (occupancy attack) with the workspace overflow fixed.
//  - v3 grew d_ws usage to 98304 B; only 91648 B is harness-proven -> probable OOB
//    fault. Head A-matrices shrunk: sdf head 1x128 (row broadcast), rgb head 4x128
//    (lane ln reads row ln&3). MFMA garbage rows never read from C are harmless.
//    New footprint: 45696 halfs = 91392 B < 91648 B proven.
//  - VGPR <= 128 (4 waves/SIMD tier): no persistent weight fragments; reload per
//    phase from L1/L2-hot wsh. __launch_bounds__(256, 4) enforces the tier.
//  - LDS = 40960 B exactly -> 4 blocks/CU (was 2): merged feat|emb buffer (64x64),
//    unpadded 64x128 h-buffers with XOR bank swizzle u ^= (row&7) on 16B units,
//    applied identically on write and read.
//  - Heads as MFMA: C-layout (col=lane&15, row=qd*4+reg) puts {r,g,b,sdf} for point
//    ln into qd==0 lanes' regs -> coalesced float4 store.

#define NPTS   (1 << 20)
#define NCHUNK (NPTS / 64)

typedef _Float16 half8   __attribute__((ext_vector_type(8)));
typedef _Float16 half4_t __attribute__((ext_vector_type(4)));
typedef float    f32x4   __attribute__((ext_vector_type(4)));

// ---- workspace layout (element offsets in halfs) ----
#define OFF_DW1T 0        // 128x32
#define OFF_DW2T 4096     // 128x128
#define OFF_RW1A 20480    // 128x32 (rgb layer1, feature part)
#define OFF_RW1B 24576    // 128x32 (rgb layer1, embed+ff part)
#define OFF_RW2T 28672    // 128x128
#define OFF_RGBA 45056    // 4x128 head A: rows0-2 = rW3 cols, row3 = 0
#define OFF_SDFA 45568    // 1x128 head A: dW3 (broadcast row)
#define HALFS_TOTAL 45696 // 91392 B <= proven 91648 B footprint

__global__ void prep_weights(const float* __restrict__ dW1,
                             const float* __restrict__ dW2,
                             const float* __restrict__ dW3,
                             const float* __restrict__ rW1,
                             const float* __restrict__ rW2,
                             const float* __restrict__ rW3,
                             _Float16* __restrict__ wsh)
{
    int tid = blockIdx.x * 256 + threadIdx.x;
    if (tid >= 16384) return;
    int n = tid >> 7, k = tid & 127;
    wsh[OFF_DW2T + n*128 + k] = (_Float16)dW2[k*128 + n];
    wsh[OFF_RW2T + n*128 + k] = (_Float16)rW2[k*128 + n];
    if (k < 32) {
        wsh[OFF_DW1T + n*32 + k] = (k < 12) ? (_Float16)dW1[k*128 + n] : (_Float16)0.f;
        wsh[OFF_RW1A + n*32 + k] = (k < 12) ? (_Float16)rW1[k*128 + n] : (_Float16)0.f;
        wsh[OFF_RW1B + n*32 + k] = (k < 29) ? (_Float16)rW1[(12 + k)*128 + n] : (_Float16)0.f;
    }
    if (n < 4)  wsh[OFF_RGBA + n*128 + k] = (n < 3) ? (_Float16)rW3[k*3 + n] : (_Float16)0.f;
    if (n == 0) wsh[OFF_SDFA + k] = (_Float16)dW3[k];
}

// h-buffer store with bank swizzle: logical half-offset ub within row n maps to
// 16B-unit u = ub>>3, swizzled u' = u ^ (n&7). Same mapping used on all reads.
__device__ __forceinline__ void store_act(_Float16* buf, int n, int ub,
                                          f32x4 acc, const float* __restrict__ bias)
{
    float4 b4 = *(const float4*)(bias + ub);
    half4_t v;
    v[0] = (_Float16)fmaxf(acc[0] + b4.x, 0.f);
    v[1] = (_Float16)fmaxf(acc[1] + b4.y, 0.f);
    v[2] = (_Float16)fmaxf(acc[2] + b4.z, 0.f);
    v[3] = (_Float16)fmaxf(acc[3] + b4.w, 0.f);
    const int u = ub >> 3;
    *(half4_t*)(buf + n*128 + ((u ^ (n & 7)) << 3) + (ub & 7)) = v;
}

#define MFMA(a, b, c) __builtin_amdgcn_mfma_f32_16x16x32_f16((a), (b), (c), 0, 0, 0)

// swizzled read address (halfs) into a 64x128 h-buffer: row n, k-slice ks*32+qd*8
#define HRD(buf, n, ks, qd) (*(const half8*)((buf) + (n)*128 + ((((ks)*4 + (qd)) ^ ((n) & 7)) << 3)))
// swizzled read into the 64x64 feat|emb buffer: unit u in 0..7 (feat 0-3, emb 4-7)
#define FRD(n, u) (*(const half8*)(fe + (n)*64 + (((u) ^ ((n) & 7)) << 3)))

__global__ __launch_bounds__(256, 4) void fastsurf_main(
    const float* __restrict__ x, const float* __restrict__ grid,
    const float* __restrict__ db1, const float* __restrict__ db2,
    const float* __restrict__ db3,
    const float* __restrict__ rb1, const float* __restrict__ rb2,
    const float* __restrict__ rb3,
    const _Float16* __restrict__ wsh,
    float* __restrict__ out)
{
    __shared__ _Float16 fe[64 * 64];    //  8192 B: [feat(32) | emb(32)] per point
    __shared__ _Float16 h1[64 * 128];   // 16384 B
    __shared__ _Float16 h2[64 * 128];   // 16384 B   -> total 40960 B = 4 blocks/CU

    const int t  = threadIdx.x;
    const int wv = t >> 6;       // wave id 0..3 -> owns output units wv*32..wv*32+31
    const int l  = t & 63;
    const int ln = l & 15;       // m within rowtile (A) / point within tile (B)
    const int qd = l >> 4;       // quad 0..3
    const int p  = t >> 2;       // gather: point 0..63
    const int q  = t & 3;        // gather: sub-thread 0..3
    const int u0 = (wv*2 + 0) * 16;
    const int u1 = (wv*2 + 1) * 16;

    const float db3v = db3[0];
    const float rb30 = rb3[0], rb31 = rb3[1], rb32 = rb3[2];

    for (int chunk = blockIdx.x; chunk < NCHUNK; chunk += gridDim.x) {
        const int pbase = chunk * 64;

        // ---------- ph0: trilinear gather + view embedding -> fe ----------
        {
            const int P = pbase + p;
            const float4 xa = *(const float4*)(x + (size_t)P*8);
            const float4 xb = *(const float4*)(x + (size_t)P*8 + 4);
            float ux = fminf(fmaxf(xa.x, 0.f), 1.f) * 159.f;
            float uy = fminf(fmaxf(xa.y, 0.f), 1.f) * 159.f;
            float uz = fminf(fmaxf(xa.z, 0.f), 1.f) * 159.f;
            float fx = fminf(floorf(ux), 158.f);
            float fy = fminf(floorf(uy), 158.f);
            float fz = fminf(floorf(uz), 158.f);
            int ix = (int)fx, iy = (int)fy, iz = (int)fz;
            float wx = ux - fx, wy = uy - fy, wz = uz - fz;

            const int bx = q >> 1, by = q & 1;   // this thread: corners (bx,by,z0/z1)
            float wxy = (bx ? wx : 1.f - wx) * (by ? wy : 1.f - wy);
            float s0 = wxy * (1.f - wz), s1 = wxy * wz;
            const float* c = grid + (size_t)(((ix + bx)*160 + (iy + by))*160 + iz) * 12;
            float4 A0 = *(const float4*)(c);
            float4 A1 = *(const float4*)(c + 4);
            float4 A2 = *(const float4*)(c + 8);
            float4 B0 = *(const float4*)(c + 12);
            float4 B1 = *(const float4*)(c + 16);
            float4 B2 = *(const float4*)(c + 20);
            float f[12];
            f[0] = s0*A0.x + s1*B0.x;  f[1] = s0*A0.y + s1*B0.y;
            f[2] = s0*A0.z + s1*B0.z;  f[3] = s0*A0.w + s1*B0.w;
            f[4] = s0*A1.x + s1*B1.x;  f[5] = s0*A1.y + s1*B1.y;
            f[6] = s0*A1.z + s1*B1.z;  f[7] = s0*A1.w + s1*B1.w;
            f[8] = s0*A2.x + s1*B2.x;  f[9] = s0*A2.y + s1*B2.y;
            f[10]= s0*A2.z + s1*B2.z;  f[11]= s0*A2.w + s1*B2.w;
#pragma unroll
            for (int j = 0; j < 12; ++j) {
                f[j] += __shfl_xor(f[j], 1);
                f[j] += __shfl_xor(f[j], 2);
            }
            // feat: units 0..3 of row p (ch >= 12 zeroed)
            half8 fv = { (_Float16)0.f,(_Float16)0.f,(_Float16)0.f,(_Float16)0.f,
                         (_Float16)0.f,(_Float16)0.f,(_Float16)0.f,(_Float16)0.f };
            if (q == 0) {
                fv[0]=(_Float16)f[0]; fv[1]=(_Float16)f[1]; fv[2]=(_Float16)f[2]; fv[3]=(_Float16)f[3];
                fv[4]=(_Float16)f[4]; fv[5]=(_Float16)f[5]; fv[6]=(_Float16)f[6]; fv[7]=(_Float16)f[7];
            } else if (q == 1) {
                fv[0]=(_Float16)f[8]; fv[1]=(_Float16)f[9]; fv[2]=(_Float16)f[10]; fv[3]=(_Float16)f[11];
            }
            *(half8*)(fe + p*64 + ((q ^ (p & 7)) << 3)) = fv;

            // emb: units 4..7 of row p: [vd(3), sin/cos f=1,2,4,8 (24), ff(2), pad]
            const float v0 = xb.y, v1 = xb.z, v2 = xb.w;
            const float ff0 = xa.w, ff1 = xb.x;
            half8 ev = { (_Float16)0.f,(_Float16)0.f,(_Float16)0.f,(_Float16)0.f,
                         (_Float16)0.f,(_Float16)0.f,(_Float16)0.f,(_Float16)0.f };
            if (q == 0) {
                ev[0]=(_Float16)v0; ev[1]=(_Float16)v1; ev[2]=(_Float16)v2;
                ev[3]=(_Float16)__sinf(v0); ev[4]=(_Float16)__sinf(v1); ev[5]=(_Float16)__sinf(v2);
                ev[6]=(_Float16)__cosf(v0); ev[7]=(_Float16)__cosf(v1);
            } else if (q == 1) {
                ev[0]=(_Float16)__cosf(v2);
                ev[1]=(_Float16)__sinf(2.f*v0); ev[2]=(_Float16)__sinf(2.f*v1); ev[3]=(_Float16)__sinf(2.f*v2);
                ev[4]=(_Float16)__cosf(2.f*v0); ev[5]=(_Float16)__cosf(2.f*v1); ev[6]=(_Float16)__cosf(2.f*v2);
                ev[7]=(_Float16)__sinf(4.f*v0);
            } else if (q == 2) {
                ev[0]=(_Float16)__sinf(4.f*v1); ev[1]=(_Float16)__sinf(4.f*v2);
                ev[2]=(_Float16)__cosf(4.f*v0); ev[3]=(_Float16)__cosf(4.f*v1); ev[4]=(_Float16)__cosf(4.f*v2);
                ev[5]=(_Float16)__sinf(8.f*v0); ev[6]=(_Float16)__sinf(8.f*v1); ev[7]=(_Float16)__sinf(8.f*v2);
            } else {
                ev[0]=(_Float16)__cosf(8.f*v0); ev[1]=(_Float16)__cosf(8.f*v1); ev[2]=(_Float16)__cosf(8.f*v2);
                ev[3]=(_Float16)ff0; ev[4]=(_Float16)ff1;
            }
            *(half8*)(fe + p*64 + (((4 + q) ^ (p & 7)) << 3)) = ev;
        }
        __syncthreads();

        // ---------- ph1: density layer 1 (K=32, feat part of fe) ----------
        {
            const half8 a0 = *(const half8*)(wsh + OFF_DW1T + (u0 + ln)*32 + qd*8);
            const half8 a1 = *(const half8*)(wsh + OFF_DW1T + (u1 + ln)*32 + qd*8);
#pragma unroll
            for (int tl = 0; tl < 4; ++tl) {
                const int n = tl*16 + ln;
                half8 b = FRD(n, qd);
                f32x4 z = {0.f, 0.f, 0.f, 0.f};
                f32x4 acc0 = MFMA(a0, b, z);
                f32x4 acc1 = MFMA(a1, b, z);
                store_act(h1, n, u0 + qd*4, acc0, db1);
                store_act(h1, n, u1 + qd*4, acc1, db1);
            }
        }
        __syncthreads();

        // ---------- ph2: density layer 2 (K=128), A reloaded from L1/L2-hot wsh ----------
        {
            half8 a_d[2][4];
#pragma unroll
            for (int rt = 0; rt < 2; ++rt)
#pragma unroll
                for (int ks = 0; ks < 4; ++ks)
                    a_d[rt][ks] = *(const half8*)(wsh + OFF_DW2T + ((wv*2 + rt)*16 + ln)*128 + ks*32 + qd*8);
#pragma unroll
            for (int tl = 0; tl < 4; ++tl) {
                const int n = tl*16 + ln;
                f32x4 acc0 = {0.f,0.f,0.f,0.f}, acc1 = {0.f,0.f,0.f,0.f};
#pragma unroll
                for (int ks = 0; ks < 4; ++ks) {
                    half8 b = HRD(h1, n, ks, qd);
                    acc0 = MFMA(a_d[0][ks], b, acc0);
                    acc1 = MFMA(a_d[1][ks], b, acc1);
                }
                store_act(h2, n, u0 + qd*4, acc0, db2);
                store_act(h2, n, u1 + qd*4, acc1, db2);
            }
        }
        __syncthreads();

        // ---------- ph3: sdf head as MFMA (A row 0 broadcast = dW3) ----------
        // Rows 1-15 of A are duplicates of row 0 -> C rows 1-15 garbage, never read.
        f32x4 sacc = {0.f, 0.f, 0.f, 0.f};
        {
            const int n = wv*16 + ln;     // this wave's 16 points
#pragma unroll
            for (int ks = 0; ks < 4; ++ks) {
                half8 a = *(const half8*)(wsh + OFF_SDFA + ks*32 + qd*8);
                half8 b = HRD(h2, n, ks, qd);
                sacc = MFMA(a, b, sacc);
            }
        }

        // ---------- ph4: rgb layer 1 (feat K=32 + emb K=32) -> h1 ----------
        // h1 last read in ph2 (pre sync2): safe to overwrite.
        {
            const half8 aa0 = *(const half8*)(wsh + OFF_RW1A + (u0 + ln)*32 + qd*8);
            const half8 aa1 = *(const half8*)(wsh + OFF_RW1A + (u1 + ln)*32 + qd*8);
            const half8 ab0 = *(const half8*)(wsh + OFF_RW1B + (u0 + ln)*32 + qd*8);
            const half8 ab1 = *(const half8*)(wsh + OFF_RW1B + (u1 + ln)*32 + qd*8);
#pragma unroll
            for (int tl = 0; tl < 4; ++tl) {
                const int n = tl*16 + ln;
                half8 bf = FRD(n, qd);
                half8 be = FRD(n, 4 + qd);
                f32x4 z = {0.f, 0.f, 0.f, 0.f};
                f32x4 acc0 = MFMA(aa0, bf, z);  acc0 = MFMA(ab0, be, acc0);
                f32x4 acc1 = MFMA(aa1, bf, z);  acc1 = MFMA(ab1, be, acc1);
                store_act(h1, n, u0 + qd*4, acc0, rb1);
                store_act(h1, n, u1 + qd*4, acc1, rb1);
            }
        }
        __syncthreads();

        // ---------- ph5: rgb layer 2 (K=128) -> h2 ----------
        // h2 last read in ph3 (pre sync4): safe to overwrite.
        {
            half8 a_r[2][4];
#pragma unroll
            for (int rt = 0; rt < 2; ++rt)
#pragma unroll
                for (int ks = 0; ks < 4; ++ks)
                    a_r[rt][ks] = *(const half8*)(wsh + OFF_RW2T + ((wv*2 + rt)*16 + ln)*128 + ks*32 + qd*8);
#pragma unroll
            for (int tl = 0; tl < 4; ++tl) {
                const int n = tl*16 + ln;
                f32x4 acc0 = {0.f,0.f,0.f,0.f}, acc1 = {0.f,0.f,0.f,0.f};
#pragma unroll
                for (int ks = 0; ks < 4; ++ks) {
                    half8 b = HRD(h1, n, ks, qd);
                    acc0 = MFMA(a_r[0][ks], b, acc0);
                    acc1 = MFMA(a_r[1][ks], b, acc1);
                }
                store_act(h2, n, u0 + qd*4, acc0, rb2);
                store_act(h2, n, u1 + qd*4, acc1, rb2);
            }
        }
        __syncthreads();

        // ---------- ph6: rgb head as MFMA + store [rgb, sdf] ----------
        // A is 4x128; lane ln reads row ln&3 -> C rows 0-2 = r,g,b (row 3 garbage,
        // rows 4-15 garbage, unused). C layout: col=lane&15 (point), row=qd*4+reg.
        {
            f32x4 racc = {0.f, 0.f, 0.f, 0.f};
            const int n = wv*16 + ln;
#pragma unroll
            for (int ks = 0; ks < 4; ++ks) {
                half8 a = *(const half8*)(wsh + OFF_RGBA + (ln & 3)*128 + ks*32 + qd*8);
                half8 b = HRD(h2, n, ks, qd);
                racc = MFMA(a, b, racc);
            }
            if (qd == 0) {
                float4 o;
                o.x = racc[0] + rb30;
                o.y = racc[1] + rb31;
                o.z = racc[2] + rb32;
                o.w = sacc[0] + db3v;
                *(float4*)(out + (size_t)(pbase + n)*4) = o;
            }
        }
        __syncthreads();  // fences ph6's h2/fe-chain reads vs next-iter rewrites
    }
}

extern "C" void kernel_launch(void* const* d_in, const int* in_sizes, int n_in,
                              void* d_out, int out_size, void* d_ws, size_t ws_size,
                              hipStream_t stream) {
    const float* x    = (const float*)d_in[0];
    const float* grid = (const float*)d_in[1];
    const float* dW1  = (const float*)d_in[2];
    const float* db1  = (const float*)d_in[3];
    const float* dW2  = (const float*)d_in[4];
    const float* db2  = (const float*)d_in[5];
    const float* dW3  = (const float*)d_in[6];
    const float* db3  = (const float*)d_in[7];
    const float* rW1  = (const float*)d_in[8];
    const float* rb1  = (const float*)d_in[9];
    const float* rW2  = (const float*)d_in[10];
    const float* rb2  = (const float*)d_in[11];
    const float* rW3  = (const float*)d_in[12];
    const float* rb3  = (const float*)d_in[13];
    float* out = (float*)d_out;

    _Float16* wsh = (_Float16*)d_ws;

    prep_weights<<<64, 256, 0, stream>>>(dW1, dW2, dW3, rW1, rW2, rW3, wsh);
    fastsurf_main<<<1024, 256, 0, stream>>>(x, grid, db1, db2, db3,
                                            rb1, rb2, rb3, wsh, out);
}

// Round 5
// 656.979 us; speedup vs baseline: 1.1939x; 1.1939x over previous
//
#include <hip/hip_runtime.h>

// FastSurf fused kernel: trilinear grid gather + density MLP + view-embed + rgb MLP.
// f16 MFMA (16x16x32), activations staged in LDS.
//
// v6 = v5 with the end-of-loop __syncthreads RESTORED.
//  - v5 evidence: removing the final barrier (6 -> 5 per chunk) produced
//    nondeterministic output across graph replays (absmax 0.0039 -> 0.0078 on the
//    same inputs). v4 with the barrier passed deterministically. Restored.
//  - Kept from v5: persistent K=128 weight fragments (64 VGPRs; keeps HBM traffic
//    at ~0.46 GB vs v4's 1.81 GB reload thrash), __launch_bounds__(256, 3)
//    (VGPR cap 168, no v4-style spill squeeze), LDS 40960 B -> 3 blocks/CU
//    (12 waves/CU vs v1's 8), MFMA heads, grid = 768 (exact residency).

#define NPTS   (1 << 20)
#define NCHUNK (NPTS / 64)

typedef _Float16 half8   __attribute__((ext_vector_type(8)));
typedef _Float16 half4_t __attribute__((ext_vector_type(4)));
typedef float    f32x4   __attribute__((ext_vector_type(4)));

// ---- workspace layout (element offsets in halfs) ----
#define OFF_DW1T 0        // 128x32
#define OFF_DW2T 4096     // 128x128
#define OFF_RW1A 20480    // 128x32 (rgb layer1, feature part)
#define OFF_RW1B 24576    // 128x32 (rgb layer1, embed+ff part)
#define OFF_RW2T 28672    // 128x128
#define OFF_RGBA 45056    // 4x128 head A: rows0-2 = rW3 cols, row3 = 0
#define OFF_SDFA 45568    // 1x128 head A: dW3 (broadcast row)
#define HALFS_TOTAL 45696 // 91392 B <= proven 91648 B footprint

__global__ void prep_weights(const float* __restrict__ dW1,
                             const float* __restrict__ dW2,
                             const float* __restrict__ dW3,
                             const float* __restrict__ rW1,
                             const float* __restrict__ rW2,
                             const float* __restrict__ rW3,
                             _Float16* __restrict__ wsh)
{
    int tid = blockIdx.x * 256 + threadIdx.x;
    if (tid >= 16384) return;
    int n = tid >> 7, k = tid & 127;
    wsh[OFF_DW2T + n*128 + k] = (_Float16)dW2[k*128 + n];
    wsh[OFF_RW2T + n*128 + k] = (_Float16)rW2[k*128 + n];
    if (k < 32) {
        wsh[OFF_DW1T + n*32 + k] = (k < 12) ? (_Float16)dW1[k*128 + n] : (_Float16)0.f;
        wsh[OFF_RW1A + n*32 + k] = (k < 12) ? (_Float16)rW1[k*128 + n] : (_Float16)0.f;
        wsh[OFF_RW1B + n*32 + k] = (k < 29) ? (_Float16)rW1[(12 + k)*128 + n] : (_Float16)0.f;
    }
    if (n < 4)  wsh[OFF_RGBA + n*128 + k] = (n < 3) ? (_Float16)rW3[k*3 + n] : (_Float16)0.f;
    if (n == 0) wsh[OFF_SDFA + k] = (_Float16)dW3[k];
}

// h-buffer store with bank swizzle: logical half-offset ub within row n maps to
// 16B-unit u = ub>>3, swizzled u' = u ^ (n&7). Same mapping used on all reads.
__device__ __forceinline__ void store_act(_Float16* buf, int n, int ub,
                                          f32x4 acc, const float* __restrict__ bias)
{
    float4 b4 = *(const float4*)(bias + ub);
    half4_t v;
    v[0] = (_Float16)fmaxf(acc[0] + b4.x, 0.f);
    v[1] = (_Float16)fmaxf(acc[1] + b4.y, 0.f);
    v[2] = (_Float16)fmaxf(acc[2] + b4.z, 0.f);
    v[3] = (_Float16)fmaxf(acc[3] + b4.w, 0.f);
    const int u = ub >> 3;
    *(half4_t*)(buf + n*128 + ((u ^ (n & 7)) << 3) + (ub & 7)) = v;
}

#define MFMA(a, b, c) __builtin_amdgcn_mfma_f32_16x16x32_f16((a), (b), (c), 0, 0, 0)

// swizzled read address (halfs) into a 64x128 h-buffer: row n, k-slice ks*32+qd*8
#define HRD(buf, n, ks, qd) (*(const half8*)((buf) + (n)*128 + ((((ks)*4 + (qd)) ^ ((n) & 7)) << 3)))
// swizzled read into the 64x64 feat|emb buffer: unit u in 0..7 (feat 0-3, emb 4-7)
#define FRD(n, u) (*(const half8*)(fe + (n)*64 + (((u) ^ ((n) & 7)) << 3)))

__global__ __launch_bounds__(256, 3) void fastsurf_main(
    const float* __restrict__ x, const float* __restrict__ grid,
    const float* __restrict__ db1, const float* __restrict__ db2,
    const float* __restrict__ db3,
    const float* __restrict__ rb1, const float* __restrict__ rb2,
    const float* __restrict__ rb3,
    const _Float16* __restrict__ wsh,
    float* __restrict__ out)
{
    __shared__ _Float16 fe[64 * 64];    //  8192 B: [feat(32) | emb(32)] per point
    __shared__ _Float16 h1[64 * 128];   // 16384 B
    __shared__ _Float16 h2[64 * 128];   // 16384 B   -> total 40960 B, 3 blocks/CU

    const int t  = threadIdx.x;
    const int wv = t >> 6;       // wave id 0..3 -> owns output units wv*32..wv*32+31
    const int l  = t & 63;
    const int ln = l & 15;       // m within rowtile (A) / point within tile (B)
    const int qd = l >> 4;       // quad 0..3
    const int p  = t >> 2;       // gather: point 0..63
    const int q  = t & 3;        // gather: sub-thread 0..3
    const int u0 = (wv*2 + 0) * 16;
    const int u1 = (wv*2 + 1) * 16;

    const float db3v = db3[0];
    const float rb30 = rb3[0], rb31 = rb3[1], rb32 = rb3[2];

    // persistent K=128 layer weight fragments (A operand): 64 VGPRs total
    half8 a_d2[2][4], a_r2[2][4];
#pragma unroll
    for (int rt = 0; rt < 2; ++rt) {
        const int m = (wv*2 + rt)*16 + ln;
#pragma unroll
        for (int ks = 0; ks < 4; ++ks) {
            a_d2[rt][ks] = *(const half8*)(wsh + OFF_DW2T + m*128 + ks*32 + qd*8);
            a_r2[rt][ks] = *(const half8*)(wsh + OFF_RW2T + m*128 + ks*32 + qd*8);
        }
    }

    for (int chunk = blockIdx.x; chunk < NCHUNK; chunk += gridDim.x) {
        const int pbase = chunk * 64;

        // ---------- ph0: trilinear gather + view embedding -> fe ----------
        {
            const int P = pbase + p;
            const float4 xa = *(const float4*)(x + (size_t)P*8);
            const float4 xb = *(const float4*)(x + (size_t)P*8 + 4);
            float ux = fminf(fmaxf(xa.x, 0.f), 1.f) * 159.f;
            float uy = fminf(fmaxf(xa.y, 0.f), 1.f) * 159.f;
            float uz = fminf(fmaxf(xa.z, 0.f), 1.f) * 159.f;
            float fx = fminf(floorf(ux), 158.f);
            float fy = fminf(floorf(uy), 158.f);
            float fz = fminf(floorf(uz), 158.f);
            int ix = (int)fx, iy = (int)fy, iz = (int)fz;
            float wx = ux - fx, wy = uy - fy, wz = uz - fz;

            const int bx = q >> 1, by = q & 1;   // this thread: corners (bx,by,z0/z1)
            float wxy = (bx ? wx : 1.f - wx) * (by ? wy : 1.f - wy);
            float s0 = wxy * (1.f - wz), s1 = wxy * wz;
            const float* c = grid + (size_t)(((ix + bx)*160 + (iy + by))*160 + iz) * 12;
            float4 A0 = *(const float4*)(c);
            float4 A1 = *(const float4*)(c + 4);
            float4 A2 = *(const float4*)(c + 8);
            float4 B0 = *(const float4*)(c + 12);
            float4 B1 = *(const float4*)(c + 16);
            float4 B2 = *(const float4*)(c + 20);
            float f[12];
            f[0] = s0*A0.x + s1*B0.x;  f[1] = s0*A0.y + s1*B0.y;
            f[2] = s0*A0.z + s1*B0.z;  f[3] = s0*A0.w + s1*B0.w;
            f[4] = s0*A1.x + s1*B1.x;  f[5] = s0*A1.y + s1*B1.y;
            f[6] = s0*A1.z + s1*B1.z;  f[7] = s0*A1.w + s1*B1.w;
            f[8] = s0*A2.x + s1*B2.x;  f[9] = s0*A2.y + s1*B2.y;
            f[10]= s0*A2.z + s1*B2.z;  f[11]= s0*A2.w + s1*B2.w;
#pragma unroll
            for (int j = 0; j < 12; ++j) {
                f[j] += __shfl_xor(f[j], 1);
                f[j] += __shfl_xor(f[j], 2);
            }
            // feat: units 0..3 of row p (ch >= 12 zeroed)
            half8 fv = { (_Float16)0.f,(_Float16)0.f,(_Float16)0.f,(_Float16)0.f,
                         (_Float16)0.f,(_Float16)0.f,(_Float16)0.f,(_Float16)0.f };
            if (q == 0) {
                fv[0]=(_Float16)f[0]; fv[1]=(_Float16)f[1]; fv[2]=(_Float16)f[2]; fv[3]=(_Float16)f[3];
                fv[4]=(_Float16)f[4]; fv[5]=(_Float16)f[5]; fv[6]=(_Float16)f[6]; fv[7]=(_Float16)f[7];
            } else if (q == 1) {
                fv[0]=(_Float16)f[8]; fv[1]=(_Float16)f[9]; fv[2]=(_Float16)f[10]; fv[3]=(_Float16)f[11];
            }
            *(half8*)(fe + p*64 + ((q ^ (p & 7)) << 3)) = fv;

            // emb: units 4..7 of row p: [vd(3), sin/cos f=1,2,4,8 (24), ff(2), pad]
            const float v0 = xb.y, v1 = xb.z, v2 = xb.w;
            const float ff0 = xa.w, ff1 = xb.x;
            half8 ev = { (_Float16)0.f,(_Float16)0.f,(_Float16)0.f,(_Float16)0.f,
                         (_Float16)0.f,(_Float16)0.f,(_Float16)0.f,(_Float16)0.f };
            if (q == 0) {
                ev[0]=(_Float16)v0; ev[1]=(_Float16)v1; ev[2]=(_Float16)v2;
                ev[3]=(_Float16)__sinf(v0); ev[4]=(_Float16)__sinf(v1); ev[5]=(_Float16)__sinf(v2);
                ev[6]=(_Float16)__cosf(v0); ev[7]=(_Float16)__cosf(v1);
            } else if (q == 1) {
                ev[0]=(_Float16)__cosf(v2);
                ev[1]=(_Float16)__sinf(2.f*v0); ev[2]=(_Float16)__sinf(2.f*v1); ev[3]=(_Float16)__sinf(2.f*v2);
                ev[4]=(_Float16)__cosf(2.f*v0); ev[5]=(_Float16)__cosf(2.f*v1); ev[6]=(_Float16)__cosf(2.f*v2);
                ev[7]=(_Float16)__sinf(4.f*v0);
            } else if (q == 2) {
                ev[0]=(_Float16)__sinf(4.f*v1); ev[1]=(_Float16)__sinf(4.f*v2);
                ev[2]=(_Float16)__cosf(4.f*v0); ev[3]=(_Float16)__cosf(4.f*v1); ev[4]=(_Float16)__cosf(4.f*v2);
                ev[5]=(_Float16)__sinf(8.f*v0); ev[6]=(_Float16)__sinf(8.f*v1); ev[7]=(_Float16)__sinf(8.f*v2);
            } else {
                ev[0]=(_Float16)__cosf(8.f*v0); ev[1]=(_Float16)__cosf(8.f*v1); ev[2]=(_Float16)__cosf(8.f*v2);
                ev[3]=(_Float16)ff0; ev[4]=(_Float16)ff1;
            }
            *(half8*)(fe + p*64 + (((4 + q) ^ (p & 7)) << 3)) = ev;
        }
        __syncthreads();

        // ---------- ph1: density layer 1 (K=32, feat part of fe) ----------
        {
            const half8 a0 = *(const half8*)(wsh + OFF_DW1T + (u0 + ln)*32 + qd*8);
            const half8 a1 = *(const half8*)(wsh + OFF_DW1T + (u1 + ln)*32 + qd*8);
#pragma unroll
            for (int tl = 0; tl < 4; ++tl) {
                const int n = tl*16 + ln;
                half8 b = FRD(n, qd);
                f32x4 z = {0.f, 0.f, 0.f, 0.f};
                f32x4 acc0 = MFMA(a0, b, z);
                f32x4 acc1 = MFMA(a1, b, z);
                store_act(h1, n, u0 + qd*4, acc0, db1);
                store_act(h1, n, u1 + qd*4, acc1, db1);
            }
        }
        __syncthreads();

        // ---------- ph2: density layer 2 (K=128, persistent A) ----------
        {
#pragma unroll
            for (int tl = 0; tl < 4; ++tl) {
                const int n = tl*16 + ln;
                f32x4 acc0 = {0.f,0.f,0.f,0.f}, acc1 = {0.f,0.f,0.f,0.f};
#pragma unroll
                for (int ks = 0; ks < 4; ++ks) {
                    half8 b = HRD(h1, n, ks, qd);
                    acc0 = MFMA(a_d2[0][ks], b, acc0);
                    acc1 = MFMA(a_d2[1][ks], b, acc1);
                }
                store_act(h2, n, u0 + qd*4, acc0, db2);
                store_act(h2, n, u1 + qd*4, acc1, db2);
            }
        }
        __syncthreads();

        // ---------- ph3: sdf head as MFMA (A row 0 broadcast = dW3) ----------
        // All A rows equal -> C rows identical; only row 0 at qd==0 consumed.
        f32x4 sacc = {0.f, 0.f, 0.f, 0.f};
        {
            const int n = wv*16 + ln;     // this wave's 16 points
#pragma unroll
            for (int ks = 0; ks < 4; ++ks) {
                half8 a = *(const half8*)(wsh + OFF_SDFA + ks*32 + qd*8);
                half8 b = HRD(h2, n, ks, qd);
                sacc = MFMA(a, b, sacc);
            }
        }

        // ---------- ph4: rgb layer 1 (feat K=32 + emb K=32) -> h1 ----------
        // h1 last read in ph2 (pre sync2): safe to overwrite.
        {
            const half8 aa0 = *(const half8*)(wsh + OFF_RW1A + (u0 + ln)*32 + qd*8);
            const half8 aa1 = *(const half8*)(wsh + OFF_RW1A + (u1 + ln)*32 + qd*8);
            const half8 ab0 = *(const half8*)(wsh + OFF_RW1B + (u0 + ln)*32 + qd*8);
            const half8 ab1 = *(const half8*)(wsh + OFF_RW1B + (u1 + ln)*32 + qd*8);
#pragma unroll
            for (int tl = 0; tl < 4; ++tl) {
                const int n = tl*16 + ln;
                half8 bf = FRD(n, qd);
                half8 be = FRD(n, 4 + qd);
                f32x4 z = {0.f, 0.f, 0.f, 0.f};
                f32x4 acc0 = MFMA(aa0, bf, z);  acc0 = MFMA(ab0, be, acc0);
                f32x4 acc1 = MFMA(aa1, bf, z);  acc1 = MFMA(ab1, be, acc1);
                store_act(h1, n, u0 + qd*4, acc0, rb1);
                store_act(h1, n, u1 + qd*4, acc1, rb1);
            }
        }
        __syncthreads();

        // ---------- ph5: rgb layer 2 (K=128, persistent A) -> h2 ----------
        // h2 last read in ph3 (pre sync3): safe to overwrite.
        {
#pragma unroll
            for (int tl = 0; tl < 4; ++tl) {
                const int n = tl*16 + ln;
                f32x4 acc0 = {0.f,0.f,0.f,0.f}, acc1 = {0.f,0.f,0.f,0.f};
#pragma unroll
                for (int ks = 0; ks < 4; ++ks) {
                    half8 b = HRD(h1, n, ks, qd);
                    acc0 = MFMA(a_r2[0][ks], b, acc0);
                    acc1 = MFMA(a_r2[1][ks], b, acc1);
                }
                store_act(h2, n, u0 + qd*4, acc0, rb2);
                store_act(h2, n, u1 + qd*4, acc1, rb2);
            }
        }
        __syncthreads();

        // ---------- ph6: rgb head as MFMA + store [rgb, sdf] ----------
        // A is 4x128; lane ln reads row ln&3 -> C rows 0-2 = r,g,b (row 3+ unused).
        // C layout: col=lane&15 (point), row=qd*4+reg -> qd==0 lanes hold r,g,b.
        {
            f32x4 racc = {0.f, 0.f, 0.f, 0.f};
            const int n = wv*16 + ln;
#pragma unroll
            for (int ks = 0; ks < 4; ++ks) {
                half8 a = *(const half8*)(wsh + OFF_RGBA + (ln & 3)*128 + ks*32 + qd*8);
                half8 b = HRD(h2, n, ks, qd);
                racc = MFMA(a, b, racc);
            }
            if (qd == 0) {
                float4 o;
                o.x = racc[0] + rb30;
                o.y = racc[1] + rb31;
                o.z = racc[2] + rb32;
                o.w = sacc[0] + db3v;
                *(float4*)(out + (size_t)(pbase + n)*4) = o;
            }
        }
        // End barrier RESTORED: removing it (v5) made output nondeterministic across
        // replays despite a paper audit claiming safety; v4 with it passed. Hardware
        // wins over the audit. Cost ~1-2%.
        __syncthreads();
    }
}

extern "C" void kernel_launch(void* const* d_in, const int* in_sizes, int n_in,
                              void* d_out, int out_size, void* d_ws, size_t ws_size,
                              hipStream_t stream) {
    const float* x    = (const float*)d_in[0];
    const float* grid = (const float*)d_in[1];
    const float* dW1  = (const float*)d_in[2];
    const float* db1  = (const float*)d_in[3];
    const float* dW2  = (const float*)d_in[4];
    const float* db2  = (const float*)d_in[5];
    const float* dW3  = (const float*)d_in[6];
    const float* db3  = (const float*)d_in[7];
    const float* rW1  = (const float*)d_in[8];
    const float* rb1  = (const float*)d_in[9];
    const float* rW2  = (const float*)d_in[10];
    const float* rb2  = (const float*)d_in[11];
    const float* rW3  = (const float*)d_in[12];
    const float* rb3  = (const float*)d_in[13];
    float* out = (float*)d_out;

    _Float16* wsh = (_Float16*)d_ws;

    prep_weights<<<64, 256, 0, stream>>>(dW1, dW2, dW3, rW1, rW2, rW3, wsh);
    // grid = 768 = 3 blocks/CU x 256 CU: exact residency (capacity guaranteed by
    // __launch_bounds__(256,3) VGPR cap + 40960B LDS; grid-stride covers NCHUNK).
    fastsurf_main<<<768, 256, 0, stream>>>(x, grid, db1, db2, db3,
                                           rb1, rb2, rb3, wsh, out);
}